// Round 7
// baseline (258.482 us; speedup 1.0000x reference)
//
#include <hip/hip_runtime.h>
#include <hip/hip_fp16.h>

namespace {

constexpr int V_ = 256, K_ = 32, C_ = 256;
constexpr int N_ = V_ * K_;            // 8192 nodes per layer
constexpr int E_ = 32768, PF_ = 4, SF_ = 16, L_ = 5;
constexpr int B_ = 512;                // batch
constexpr int NCH = 64;                // root partial chunks
constexpr int BC = 64;                 // batch elems per XCD chunk (8 chunks)

constexpr float LOG2E = 1.4426950408889634f;
constexpr float LN2   = 0.6931471805599453f;

__device__ __forceinline__ float2 h2f(uint32_t u) {
    __half2 h = *reinterpret_cast<__half2*>(&u);
    return __half22float2(h);
}
__device__ __forceinline__ uint32_t f2h(float a, float b) {
    __half2 h = __floats2half2_rn(a, b);
    return *reinterpret_cast<uint32_t*>(&h);
}

// ---- input layer: nm[vk][b..b+7] = lp[vk][inputs[b..b+7][v]] * LOG2E ----
__global__ void input_layer_k(const int* __restrict__ inp,   // [B,V]
                              const float* __restrict__ lp,  // [V,K,C]
                              uint32_t* __restrict__ nm)     // [N,B] f16 (log2 domain)
{
    const int t = blockIdx.x * blockDim.x + threadIdx.x;  // V*K*(B/8)
    const int b = (t & 63) << 3;
    const int vk = t >> 6;
    const int v = vk >> 5;
    const float* row = lp + (size_t)vk * C_;
    uint4 r;
    r.x = f2h(row[inp[(b + 0) * V_ + v]] * LOG2E, row[inp[(b + 1) * V_ + v]] * LOG2E);
    r.y = f2h(row[inp[(b + 2) * V_ + v]] * LOG2E, row[inp[(b + 3) * V_ + v]] * LOG2E);
    r.z = f2h(row[inp[(b + 4) * V_ + v]] * LOG2E, row[inp[(b + 5) * V_ + v]] * LOG2E);
    r.w = f2h(row[inp[(b + 6) * V_ + v]] * LOG2E, row[inp[(b + 7) * V_ + v]] * LOG2E);
    *reinterpret_cast<uint4*>(nm + ((size_t)vk * B_ + b) / 2) = r;
}

// one child element: gather its 4 product children from nm, sum (log-product),
// add sum-weight -> xs[0..7] for this thread's 8 batch slots
__device__ __forceinline__ void child8(const uint32_t* __restrict__ nmi, size_t bo,
                                       const int4 p, float w, float* xs)
{
    const uint4 a = *reinterpret_cast<const uint4*>(nmi + (size_t)p.x * (B_ / 2) + bo);
    const uint4 b = *reinterpret_cast<const uint4*>(nmi + (size_t)p.y * (B_ / 2) + bo);
    const uint4 c = *reinterpret_cast<const uint4*>(nmi + (size_t)p.z * (B_ / 2) + bo);
    const uint4 d = *reinterpret_cast<const uint4*>(nmi + (size_t)p.w * (B_ / 2) + bo);
    {
        const float2 fa = h2f(a.x), fb = h2f(b.x), fc = h2f(c.x), fd = h2f(d.x);
        xs[0] = (fa.x + fb.x) + (fc.x + fd.x) + w;
        xs[1] = (fa.y + fb.y) + (fc.y + fd.y) + w;
    }
    {
        const float2 fa = h2f(a.y), fb = h2f(b.y), fc = h2f(c.y), fd = h2f(d.y);
        xs[2] = (fa.x + fb.x) + (fc.x + fd.x) + w;
        xs[3] = (fa.y + fb.y) + (fc.y + fd.y) + w;
    }
    {
        const float2 fa = h2f(a.z), fb = h2f(b.z), fc = h2f(c.z), fd = h2f(d.z);
        xs[4] = (fa.x + fb.x) + (fc.x + fd.x) + w;
        xs[5] = (fa.y + fb.y) + (fc.y + fd.y) + w;
    }
    {
        const float2 fa = h2f(a.w), fb = h2f(b.w), fc = h2f(c.w), fd = h2f(d.w);
        xs[6] = (fa.x + fb.x) + (fc.x + fd.x) + w;
        xs[7] = (fa.y + fb.y) + (fc.y + fd.y) + w;
    }
}

// ---- fused layer: nm_out[n][bs] = LSE2_s( sum_f nm_in[pc[sc[n][s]][f]][bs] + lw2[n][s] )
// batch-chunked per XCD (blockIdx & 7); 32 node-rows x 8 lanes per block
__global__ __launch_bounds__(256, 4) void layer_k(
    const uint32_t* __restrict__ nmi,  // [N,B] f16 log2
    const int* __restrict__ pc,        // [E,PF]
    const int* __restrict__ sc,        // [N,SF]
    const float* __restrict__ lw,      // [N,SF] natural log
    uint32_t* __restrict__ nmo)        // [N,B] f16 log2
{
    const int bchunk = blockIdx.x & 7;
    const int n = (blockIdx.x >> 3) * 32 + (threadIdx.x >> 3);
    const size_t bo = (size_t)bchunk * (BC / 2) + (threadIdx.x & 7) * 4;

    int4 scv[4];
    float4 lwv[4];
    #pragma unroll
    for (int q = 0; q < 4; ++q) {
        scv[q] = *reinterpret_cast<const int4*>(sc + (size_t)n * SF_ + q * 4);
        lwv[q] = *reinterpret_cast<const float4*>(lw + (size_t)n * SF_ + q * 4);
    }
    const int*   sci = reinterpret_cast<const int*>(scv);
    const float* lwf = reinterpret_cast<const float*>(lwv);

    float m[8], acc[8];
    #pragma unroll
    for (int j = 0; j < 8; ++j) { m[j] = -3.0e38f; acc[j] = 0.f; }

    #pragma unroll
    for (int g = 0; g < 8; ++g) {                 // 8 groups of 2 children
        const int4 p0 = *reinterpret_cast<const int4*>(pc + (size_t)sci[2 * g + 0] * 4);
        const int4 p1 = *reinterpret_cast<const int4*>(pc + (size_t)sci[2 * g + 1] * 4);
        const float w0 = lwf[2 * g + 0] * LOG2E;
        const float w1 = lwf[2 * g + 1] * LOG2E;
        float x0[8], x1[8];
        child8(nmi, bo, p0, w0, x0);
        child8(nmi, bo, p1, w1, x1);
        #pragma unroll
        for (int j = 0; j < 8; ++j) {
            const float cm = fmaxf(x0[j], x1[j]);
            const float mm = fmaxf(m[j], cm);
            acc[j] = acc[j] * exp2f(m[j] - mm) + exp2f(x0[j] - mm) + exp2f(x1[j] - mm);
            m[j] = mm;
        }
    }

    uint4 r;
    r.x = f2h(m[0] + log2f(acc[0]), m[1] + log2f(acc[1]));
    r.y = f2h(m[2] + log2f(acc[2]), m[3] + log2f(acc[3]));
    r.z = f2h(m[4] + log2f(acc[4]), m[5] + log2f(acc[5]));
    r.w = f2h(m[6] + log2f(acc[6]), m[7] + log2f(acc[7]));
    *reinterpret_cast<uint4*>(nmo + (size_t)n * (B_ / 2) + bo) = r;
}

// ---- root stage 1: per-chunk online LSE2 over nodes ----
__global__ void root_part_k(const __half* __restrict__ nm,  // [N,B] f16 log2
                            const float* __restrict__ rw,   // [N] natural log
                            float* __restrict__ pm,         // [NCH,B]
                            float* __restrict__ ps)         // [NCH,B]
{
    const int b = blockIdx.x * blockDim.x + threadIdx.x;
    const int ch = blockIdx.y;
    const int n0 = ch * (N_ / NCH);
    float m = -3.0e38f, s = 0.f;
    for (int i = 0; i < N_ / NCH; ++i) {
        const int n = n0 + i;
        const float x = __half2float(nm[(size_t)n * B_ + b]) + rw[n] * LOG2E;
        const float mn = fmaxf(m, x);
        s = s * exp2f(m - mn) + exp2f(x - mn);
        m = mn;
    }
    pm[ch * B_ + b] = m;
    ps[ch * B_ + b] = s;
}

// ---- root stage 2: combine, convert back to natural log ----
__global__ void root_comb_k(const float* __restrict__ pm,
                            const float* __restrict__ ps,
                            float* __restrict__ out)        // [B]
{
    const int b = blockIdx.x * blockDim.x + threadIdx.x;
    float m = -3.0e38f;
    for (int ch = 0; ch < NCH; ++ch) m = fmaxf(m, pm[ch * B_ + b]);
    float s = 0.f;
    for (int ch = 0; ch < NCH; ++ch) s += ps[ch * B_ + b] * exp2f(pm[ch * B_ + b] - m);
    out[b] = (m + log2f(s)) * LN2;
}

} // namespace

extern "C" void kernel_launch(void* const* d_in, const int* in_sizes, int n_in,
                              void* d_out, int out_size, void* d_ws, size_t ws_size,
                              hipStream_t stream) {
    const int*   inp = (const int*)d_in[0];     // [B,V]
    const float* lp  = (const float*)d_in[1];   // [V,K,C]
    const int*   pc  = (const int*)d_in[2];     // [L,E,PF]
    const int*   sc  = (const int*)d_in[3];     // [L,N,SF]
    const float* lw  = (const float*)d_in[4];   // [L,N,SF]
    const float* rw  = (const float*)d_in[5];   // [N]
    float*       out = (float*)d_out;           // [B,1]

    uint32_t* nm0 = (uint32_t*)d_ws;                     // 8 MB (f16, ping)
    uint32_t* nm1 = nm0 + (size_t)N_ * B_ / 2;           // 8 MB (f16, pong)
    float*    pm  = (float*)(nm1 + (size_t)N_ * B_ / 2);
    float*    ps  = pm + (size_t)NCH * B_;

    input_layer_k<<<(V_ * K_ * (B_ / 8)) / 256, 256, 0, stream>>>(inp, lp, nm0);

    // fused product+sum per layer, nm ping-pong; (N/32)*8 = 2048 blocks
    for (int l = 0; l < L_; ++l) {
        const uint32_t* src = (l & 1) ? nm1 : nm0;
        uint32_t*       dst = (l & 1) ? nm0 : nm1;
        layer_k<<<(N_ / 32) * 8, 256, 0, stream>>>(
            src, pc + (size_t)l * E_ * PF_,
            sc + (size_t)l * N_ * SF_, lw + (size_t)l * N_ * SF_, dst);
    }
    const uint32_t* fin = (L_ & 1) ? nm1 : nm0;          // L=5 -> nm1

    root_part_k<<<dim3(B_ / 256, NCH), 256, 0, stream>>>((const __half*)fin, rw, pm, ps);
    root_comb_k<<<B_ / 256, 256, 0, stream>>>(pm, ps, out);
}

// Round 9
// 203.052 us; speedup vs baseline: 1.2730x; 1.2730x over previous
//
#include <hip/hip_runtime.h>
#include <hip/hip_fp16.h>

namespace {

constexpr int V_ = 256, K_ = 32, C_ = 256;
constexpr int N_ = V_ * K_;            // 8192 nodes per layer
constexpr int E_ = 32768, PF_ = 4, SF_ = 16, L_ = 5;
constexpr int B_ = 512;                // batch
constexpr int NCH = 64;                // root partial chunks
constexpr int BC = 64;                 // batch elems per XCD chunk (8 chunks)

constexpr float LOG2E = 1.4426950408889634f;
constexpr float LN2   = 0.6931471805599453f;

typedef _Float16 h2v __attribute__((ext_vector_type(2)));  // native packed f16

__device__ __forceinline__ uint32_t f2h(float a, float b) {
    __half2 h = __floats2half2_rn(a, b);
    return *reinterpret_cast<uint32_t*>(&h);
}
__device__ __forceinline__ h2v splat2(float x) {
    const _Float16 h = (_Float16)x;
    h2v r; r.x = h; r.y = h; return r;
}
__device__ __forceinline__ float2 h2f(h2v v) {
    return make_float2((float)v.x, (float)v.y);
}

// ---- input layer: nm[vk][b..b+7] = lp[vk][inputs[b..b+7][v]] * LOG2E ----
__global__ void input_layer_k(const int* __restrict__ inp,   // [B,V]
                              const float* __restrict__ lp,  // [V,K,C]
                              uint32_t* __restrict__ nm)     // [N,B] f16 (log2 domain)
{
    const int t = blockIdx.x * blockDim.x + threadIdx.x;  // V*K*(B/8)
    const int b = (t & 63) << 3;
    const int vk = t >> 6;
    const int v = vk >> 5;
    const float* row = lp + (size_t)vk * C_;
    uint4 r;
    r.x = f2h(row[inp[(b + 0) * V_ + v]] * LOG2E, row[inp[(b + 1) * V_ + v]] * LOG2E);
    r.y = f2h(row[inp[(b + 2) * V_ + v]] * LOG2E, row[inp[(b + 3) * V_ + v]] * LOG2E);
    r.z = f2h(row[inp[(b + 4) * V_ + v]] * LOG2E, row[inp[(b + 5) * V_ + v]] * LOG2E);
    r.w = f2h(row[inp[(b + 6) * V_ + v]] * LOG2E, row[inp[(b + 7) * V_ + v]] * LOG2E);
    *reinterpret_cast<uint4*>(nm + ((size_t)vk * B_ + b) / 2) = r;
}

__device__ __forceinline__ void load4h2(const uint32_t* __restrict__ p, size_t off,
                                        h2v o[4]) {
    const uint4 u = *reinterpret_cast<const uint4*>(p + off);
    o[0] = *reinterpret_cast<const h2v*>(&u.x);
    o[1] = *reinterpret_cast<const h2v*>(&u.y);
    o[2] = *reinterpret_cast<const h2v*>(&u.z);
    o[3] = *reinterpret_cast<const h2v*>(&u.w);
}

// ---- fused layer, packed-f16 product + full-max LSE ----
// nm_out[n][bs] = LSE2_s( sum_f nm_in[pc[sc[n][s]][f]][bs] + lw2[n][s] )
// batch-chunked per XCD (blockIdx & 7); 32 node-rows x 8 lanes per block
__global__ __launch_bounds__(256, 4) void layer_k(
    const uint32_t* __restrict__ nmi,  // [N,B] f16 log2
    const int* __restrict__ pc,        // [E,PF]
    const int* __restrict__ sc,        // [N,SF]
    const float* __restrict__ lw,      // [N,SF] natural log
    uint32_t* __restrict__ nmo)        // [N,B] f16 log2
{
    const int bchunk = blockIdx.x & 7;
    const int n = (blockIdx.x >> 3) * 32 + (threadIdx.x >> 3);
    const size_t bo = (size_t)bchunk * (BC / 2) + (threadIdx.x & 7) * 4;

    int4 scv[4];
    float4 lwv[4];
    #pragma unroll
    for (int q = 0; q < 4; ++q) {
        scv[q] = *reinterpret_cast<const int4*>(sc + (size_t)n * SF_ + q * 4);
        lwv[q] = *reinterpret_cast<const float4*>(lw + (size_t)n * SF_ + q * 4);
    }
    const int*   sci = reinterpret_cast<const int*>(scv);
    const float* lwf = reinterpret_cast<const float*>(lwv);

    h2v xs[SF_][4];                 // 64 VGPRs: all 16 children, packed
    h2v m2[4];
    #pragma unroll
    for (int q = 0; q < 4; ++q) m2[q] = splat2(-30000.0f);

    // pass 1: packed product-sum + weight, track packed max (v_pk_add/max_f16)
    #pragma unroll
    for (int s = 0; s < SF_; ++s) {
        const int4 p = *reinterpret_cast<const int4*>(pc + (size_t)sci[s] * 4);
        h2v a[4], b[4], c[4], d[4];
        load4h2(nmi, (size_t)p.x * (B_ / 2) + bo, a);
        load4h2(nmi, (size_t)p.y * (B_ / 2) + bo, b);
        load4h2(nmi, (size_t)p.z * (B_ / 2) + bo, c);
        load4h2(nmi, (size_t)p.w * (B_ / 2) + bo, d);
        const h2v w2 = splat2(lwf[s] * LOG2E);
        #pragma unroll
        for (int q = 0; q < 4; ++q) {
            const h2v t = ((a[q] + b[q]) + (c[q] + d[q])) + w2;
            xs[s][q] = t;
            m2[q] = __builtin_elementwise_max(m2[q], t);
        }
    }

    // pass 2: exact 16 exps per slot in f32
    float acc[8];
    #pragma unroll
    for (int j = 0; j < 8; ++j) acc[j] = 0.f;
    #pragma unroll
    for (int s = 0; s < SF_; ++s) {
        #pragma unroll
        for (int q = 0; q < 4; ++q) {
            const float2 f = h2f(xs[s][q] - m2[q]);
            acc[2 * q + 0] += exp2f(f.x);
            acc[2 * q + 1] += exp2f(f.y);
        }
    }

    uint4 r;
    {
        const float2 f0 = h2f(m2[0]);
        const float2 f1 = h2f(m2[1]);
        r.x = f2h(f0.x + log2f(acc[0]), f0.y + log2f(acc[1]));
        r.y = f2h(f1.x + log2f(acc[2]), f1.y + log2f(acc[3]));
    }
    {
        const float2 f2v = h2f(m2[2]);
        const float2 f3v = h2f(m2[3]);
        r.z = f2h(f2v.x + log2f(acc[4]), f2v.y + log2f(acc[5]));
        r.w = f2h(f3v.x + log2f(acc[6]), f3v.y + log2f(acc[7]));
    }
    *reinterpret_cast<uint4*>(nmo + (size_t)n * (B_ / 2) + bo) = r;
}

// ---- root stage 1: per-chunk online LSE2 over nodes ----
__global__ void root_part_k(const __half* __restrict__ nm,  // [N,B] f16 log2
                            const float* __restrict__ rw,   // [N] natural log
                            float* __restrict__ pm,         // [NCH,B]
                            float* __restrict__ ps)         // [NCH,B]
{
    const int b = blockIdx.x * blockDim.x + threadIdx.x;
    const int ch = blockIdx.y;
    const int n0 = ch * (N_ / NCH);
    float m = -3.0e38f, s = 0.f;
    for (int i = 0; i < N_ / NCH; ++i) {
        const int n = n0 + i;
        const float x = __half2float(nm[(size_t)n * B_ + b]) + rw[n] * LOG2E;
        const float mn = fmaxf(m, x);
        s = s * exp2f(m - mn) + exp2f(x - mn);
        m = mn;
    }
    pm[ch * B_ + b] = m;
    ps[ch * B_ + b] = s;
}

// ---- root stage 2: combine, convert back to natural log ----
__global__ void root_comb_k(const float* __restrict__ pm,
                            const float* __restrict__ ps,
                            float* __restrict__ out)        // [B]
{
    const int b = blockIdx.x * blockDim.x + threadIdx.x;
    float m = -3.0e38f;
    for (int ch = 0; ch < NCH; ++ch) m = fmaxf(m, pm[ch * B_ + b]);
    float s = 0.f;
    for (int ch = 0; ch < NCH; ++ch) s += ps[ch * B_ + b] * exp2f(pm[ch * B_ + b] - m);
    out[b] = (m + log2f(s)) * LN2;
}

} // namespace

extern "C" void kernel_launch(void* const* d_in, const int* in_sizes, int n_in,
                              void* d_out, int out_size, void* d_ws, size_t ws_size,
                              hipStream_t stream) {
    const int*   inp = (const int*)d_in[0];     // [B,V]
    const float* lp  = (const float*)d_in[1];   // [V,K,C]
    const int*   pc  = (const int*)d_in[2];     // [L,E,PF]
    const int*   sc  = (const int*)d_in[3];     // [L,N,SF]
    const float* lw  = (const float*)d_in[4];   // [L,N,SF]
    const float* rw  = (const float*)d_in[5];   // [N]
    float*       out = (float*)d_out;           // [B,1]

    uint32_t* nm0 = (uint32_t*)d_ws;                     // 8 MB (f16, ping)
    uint32_t* nm1 = nm0 + (size_t)N_ * B_ / 2;           // 8 MB (f16, pong)
    float*    pm  = (float*)(nm1 + (size_t)N_ * B_ / 2);
    float*    ps  = pm + (size_t)NCH * B_;

    input_layer_k<<<(V_ * K_ * (B_ / 8)) / 256, 256, 0, stream>>>(inp, lp, nm0);

    for (int l = 0; l < L_; ++l) {
        const uint32_t* src = (l & 1) ? nm1 : nm0;
        uint32_t*       dst = (l & 1) ? nm0 : nm1;
        layer_k<<<(N_ / 32) * 8, 256, 0, stream>>>(
            src, pc + (size_t)l * E_ * PF_,
            sc + (size_t)l * N_ * SF_, lw + (size_t)l * N_ * SF_, dst);
    }
    const uint32_t* fin = (L_ & 1) ? nm1 : nm0;          // L=5 -> nm1

    root_part_k<<<dim3(B_ / 256, NCH), 256, 0, stream>>>((const __half*)fin, rw, pm, ps);
    root_comb_k<<<B_ / 256, 256, 0, stream>>>(pm, ps, out);
}

// Round 10
// 162.957 us; speedup vs baseline: 1.5862x; 1.2460x over previous
//
#include <hip/hip_runtime.h>
#include <hip/hip_fp16.h>

namespace {

constexpr int V_ = 256, K_ = 32, C_ = 256;
constexpr int N_ = V_ * K_;            // 8192 nodes per layer
constexpr int E_ = 32768, PF_ = 4, SF_ = 16, L_ = 5;
constexpr int B_ = 512;                // batch
constexpr int NCH = 64;                // root partial chunks
constexpr int NSLICE = B_ / 8;         // 64 batch slices of 8
constexpr int NCHK = 4;                // node chunks per layer
constexpr int NPB = N_ / NCHK;         // 2048 nodes per block

constexpr float LOG2E = 1.4426950408889634f;
constexpr float LN2   = 0.6931471805599453f;

typedef _Float16 h2v __attribute__((ext_vector_type(2)));  // packed f16

__device__ __forceinline__ uint32_t f2h(float a, float b) {
    __half2 h = __floats2half2_rn(a, b);
    return *reinterpret_cast<uint32_t*>(&h);
}
__device__ __forceinline__ h2v splat2h(uint32_t bits) {   // low 16 bits -> both lanes
    const _Float16 h = __builtin_bit_cast(_Float16, (unsigned short)(bits & 0xffffu));
    h2v r; r.x = h; r.y = h; return r;
}
__device__ __forceinline__ float2 h2f2(h2v v) {
    return make_float2((float)v.x, (float)v.y);
}
__device__ __forceinline__ h2v u2h(uint32_t u) { return __builtin_bit_cast(h2v, u); }

// ---- prep: pcx[l][n][s] = ushort4(pc[l][sc[l][n][s]]), lwh = f16(lw * LOG2E) ----
__global__ void prep_k(const int* __restrict__ sc,    // [L,N,SF]
                       const int* __restrict__ pc,    // [L,E,PF]
                       const float* __restrict__ lw,  // [L,N,SF]
                       ushort4* __restrict__ pcx,     // [L,N,SF]
                       __half* __restrict__ lwh)      // [L,N,SF]
{
    const int t = blockIdx.x * blockDim.x + threadIdx.x;  // L*N*SF = 655360
    const int l = t >> 17;                                // / (N*SF = 131072)
    const int e = sc[t];
    const int4 p = *reinterpret_cast<const int4*>(pc + ((size_t)l * E_ + e) * 4);
    ushort4 u;
    u.x = (unsigned short)p.x; u.y = (unsigned short)p.y;
    u.z = (unsigned short)p.z; u.w = (unsigned short)p.w;
    pcx[t] = u;
    lwh[t] = __float2half(lw[t] * LOG2E);
}

// ---- input layer: nm[bs][vk][0..7] = lp[vk][inputs[bs*8+j][v]] * LOG2E ----
__global__ void input_layer_k(const int* __restrict__ inp,   // [B,V]
                              const float* __restrict__ lp,  // [V,K,C]
                              uint4* __restrict__ nm)        // [NSLICE][N] rows of 8 f16
{
    const int t = blockIdx.x * blockDim.x + threadIdx.x;  // NSLICE * N
    const int vk = t & (N_ - 1);
    const int bs = t >> 13;
    const int v = vk >> 5;
    const int b = bs * 8;
    const float* row = lp + (size_t)vk * C_;
    uint4 r;
    r.x = f2h(row[inp[(b + 0) * V_ + v]] * LOG2E, row[inp[(b + 1) * V_ + v]] * LOG2E);
    r.y = f2h(row[inp[(b + 2) * V_ + v]] * LOG2E, row[inp[(b + 3) * V_ + v]] * LOG2E);
    r.z = f2h(row[inp[(b + 4) * V_ + v]] * LOG2E, row[inp[(b + 5) * V_ + v]] * LOG2E);
    r.w = f2h(row[inp[(b + 6) * V_ + v]] * LOG2E, row[inp[(b + 7) * V_ + v]] * LOG2E);
    nm[(size_t)bs * N_ + vk] = r;
}

// ---- fused layer, LDS-staged nm slice ----
// grid = NSLICE * NCHK blocks (bs = blockIdx & 63 -> XCD-stable), 1024 threads
__global__ __launch_bounds__(1024, 4) void layer_k(
    const uint4* __restrict__ nmi,   // [NSLICE][N] rows of 8 f16 (log2 domain)
    const uint4* __restrict__ pcx,   // [N][8] : 16 ushort4 per node (child rows)
    const uint4* __restrict__ lwh,   // [N][2] : 16 f16 weights per node (log2)
    uint4* __restrict__ nmo)         // [NSLICE][N]
{
    __shared__ uint4 lds[N_];                       // 128 KB: full node slice
    const int bs = blockIdx.x & (NSLICE - 1);
    const int nc = blockIdx.x >> 6;

    const uint4* src = nmi + (size_t)bs * N_;
    for (int i = threadIdx.x; i < N_; i += 1024) lds[i] = src[i];
    __syncthreads();

    #pragma unroll
    for (int r = 0; r < 2; ++r) {
        const int n = nc * NPB + r * 1024 + threadIdx.x;
        const uint4* pr = pcx + (size_t)n * 8;
        const uint4* wr = lwh + (size_t)n * 2;

        h2v xs[8][4], m2[4], cm[4];
        float acc[8];

        // helper expanded inline via lambda
        auto children8 = [&](const uint4 pw0, const uint4 pw1, const uint4 pw2,
                             const uint4 pw3, const uint4 wv) {
            auto child = [&](int s8, uint32_t rr0, uint32_t rr1, uint32_t wbits) {
                const uint4 a = lds[rr0 & 0xffffu];
                const uint4 b = lds[rr0 >> 16];
                const uint4 c = lds[rr1 & 0xffffu];
                const uint4 d = lds[rr1 >> 16];
                const h2v w2 = splat2h(wbits);
                #pragma unroll
                for (int q = 0; q < 4; ++q) {
                    h2v t = (u2h((&a.x)[q]) + u2h((&b.x)[q]))
                          + (u2h((&c.x)[q]) + u2h((&d.x)[q]));
                    t = t + w2;
                    xs[s8][q] = t;
                    cm[q] = __builtin_elementwise_max(cm[q], t);
                }
            };
            child(0, pw0.x, pw0.y, wv.x);
            child(1, pw0.z, pw0.w, wv.x >> 16);
            child(2, pw1.x, pw1.y, wv.y);
            child(3, pw1.z, pw1.w, wv.y >> 16);
            child(4, pw2.x, pw2.y, wv.z);
            child(5, pw2.z, pw2.w, wv.z >> 16);
            child(6, pw3.x, pw3.y, wv.w);
            child(7, pw3.z, pw3.w, wv.w >> 16);
        };

        // ---- half 0 ----
        #pragma unroll
        for (int q = 0; q < 4; ++q) cm[q] = splat2h(0xF7FFu); // f16 -30000-ish (0xF7FF = -65504? use constant below)
        // use an explicit very-negative f16: bits 0xF400 = -16384
        #pragma unroll
        for (int q = 0; q < 4; ++q) cm[q] = splat2h(0xF400u);
        children8(pr[0], pr[1], pr[2], pr[3], wr[0]);
        #pragma unroll
        for (int q = 0; q < 4; ++q) m2[q] = cm[q];
        #pragma unroll
        for (int j = 0; j < 8; ++j) acc[j] = 0.f;
        #pragma unroll
        for (int s = 0; s < 8; ++s) {
            #pragma unroll
            for (int q = 0; q < 4; ++q) {
                const float2 f = h2f2(xs[s][q] - m2[q]);
                acc[2 * q + 0] += exp2f(f.x);
                acc[2 * q + 1] += exp2f(f.y);
            }
        }

        // ---- half 1 ----
        #pragma unroll
        for (int q = 0; q < 4; ++q) cm[q] = splat2h(0xF400u);
        children8(pr[4], pr[5], pr[6], pr[7], wr[1]);
        #pragma unroll
        for (int q = 0; q < 4; ++q) {
            const h2v mm = __builtin_elementwise_max(m2[q], cm[q]);
            const float2 df = h2f2(m2[q] - mm);
            acc[2 * q + 0] *= exp2f(df.x);
            acc[2 * q + 1] *= exp2f(df.y);
            m2[q] = mm;
        }
        #pragma unroll
        for (int s = 0; s < 8; ++s) {
            #pragma unroll
            for (int q = 0; q < 4; ++q) {
                const float2 f = h2f2(xs[s][q] - m2[q]);
                acc[2 * q + 0] += exp2f(f.x);
                acc[2 * q + 1] += exp2f(f.y);
            }
        }

        uint4 o;
        {
            const float2 f0 = h2f2(m2[0]);
            const float2 f1 = h2f2(m2[1]);
            o.x = f2h(f0.x + log2f(acc[0]), f0.y + log2f(acc[1]));
            o.y = f2h(f1.x + log2f(acc[2]), f1.y + log2f(acc[3]));
        }
        {
            const float2 f2v = h2f2(m2[2]);
            const float2 f3v = h2f2(m2[3]);
            o.z = f2h(f2v.x + log2f(acc[4]), f2v.y + log2f(acc[5]));
            o.w = f2h(f3v.x + log2f(acc[6]), f3v.y + log2f(acc[7]));
        }
        nmo[(size_t)bs * N_ + n] = o;
    }
}

// ---- root stage 1: per-chunk online LSE2 over nodes (batch-major layout) ----
__global__ void root_part_k(const __half* __restrict__ nm,  // [NSLICE][N][8] f16 log2
                            const float* __restrict__ rw,   // [N] natural log
                            float* __restrict__ pm,         // [NCH,B]
                            float* __restrict__ ps)         // [NCH,B]
{
    const int b = blockIdx.x * blockDim.x + threadIdx.x;
    const int ch = blockIdx.y;
    const int n0 = ch * (N_ / NCH);
    const int bs = b >> 3, j = b & 7;
    float m = -3.0e38f, s = 0.f;
    for (int i = 0; i < N_ / NCH; ++i) {
        const int n = n0 + i;
        const float x = __half2float(nm[((size_t)bs * N_ + n) * 8 + j]) + rw[n] * LOG2E;
        const float mn = fmaxf(m, x);
        s = s * exp2f(m - mn) + exp2f(x - mn);
        m = mn;
    }
    pm[ch * B_ + b] = m;
    ps[ch * B_ + b] = s;
}

// ---- root stage 2: combine, back to natural log ----
__global__ void root_comb_k(const float* __restrict__ pm,
                            const float* __restrict__ ps,
                            float* __restrict__ out)        // [B]
{
    const int b = blockIdx.x * blockDim.x + threadIdx.x;
    float m = -3.0e38f;
    for (int ch = 0; ch < NCH; ++ch) m = fmaxf(m, pm[ch * B_ + b]);
    float s = 0.f;
    for (int ch = 0; ch < NCH; ++ch) s += ps[ch * B_ + b] * exp2f(pm[ch * B_ + b] - m);
    out[b] = (m + log2f(s)) * LN2;
}

} // namespace

extern "C" void kernel_launch(void* const* d_in, const int* in_sizes, int n_in,
                              void* d_out, int out_size, void* d_ws, size_t ws_size,
                              hipStream_t stream) {
    const int*   inp = (const int*)d_in[0];     // [B,V]
    const float* lp  = (const float*)d_in[1];   // [V,K,C]
    const int*   pc  = (const int*)d_in[2];     // [L,E,PF]
    const int*   sc  = (const int*)d_in[3];     // [L,N,SF]
    const float* lw  = (const float*)d_in[4];   // [L,N,SF]
    const float* rw  = (const float*)d_in[5];   // [N]
    float*       out = (float*)d_out;           // [B,1]

    uint4*   nm0 = (uint4*)d_ws;                             // 64*8192*16 = 8 MB
    uint4*   nm1 = nm0 + (size_t)NSLICE * N_;                // 8 MB
    ushort4* pcx = (ushort4*)(nm1 + (size_t)NSLICE * N_);    // 5*8192*16*8 = 5 MB
    __half*  lwh = (__half*)(pcx + (size_t)L_ * N_ * SF_);   // 1.25 MB
    float*   pm  = (float*)(lwh + (size_t)L_ * N_ * SF_);
    float*   ps  = pm + (size_t)NCH * B_;

    prep_k<<<(L_ * N_ * SF_) / 256, 256, 0, stream>>>(sc, pc, lw, pcx, lwh);
    input_layer_k<<<(NSLICE * N_) / 256, 256, 0, stream>>>(inp, lp, nm0);

    for (int l = 0; l < L_; ++l) {
        const uint4* srcb = (l & 1) ? nm1 : nm0;
        uint4*       dstb = (l & 1) ? nm0 : nm1;
        layer_k<<<NSLICE * NCHK, 1024, 0, stream>>>(
            srcb,
            (const uint4*)(pcx + (size_t)l * N_ * SF_),
            (const uint4*)(lwh + (size_t)l * N_ * SF_),
            dstb);
    }
    const uint4* fin = (L_ & 1) ? nm1 : nm0;                 // L=5 -> nm1

    root_part_k<<<dim3(B_ / 256, NCH), 256, 0, stream>>>((const __half*)fin, rw, pm, ps);
    root_comb_k<<<B_ / 256, 256, 0, stream>>>(pm, ps, out);
}